// Round 14
// baseline (188.590 us; speedup 1.0000x reference)
//
#include <hip/hip_runtime.h>

// BindingFormer fused pipeline for MI355X (gfx950), round 15.
// r14b: total 182.0 (best), edge 72.2, absmax 0.0195. edge_k latency-bound
// at 3 blocks/CU (Mfma 8%, VALU 40%, HBM 13%). r9d's 4-blocks thrash now
// has a mechanism: 256-B TCC lines, but each GEMM2 wave wrote only a 128-B
// span per edge row (2n x 2e mapping splits each 256-B half-line across two
// waves) -> partial-line RMW under 4-block pressure (FETCH +19MB, WRITE
// 1.5x — both match). r15 single-variable test: GEMM2 remapped 4n x 1e
// (wave owns full 256-B span of its 16 edge rows), H 512B+XOR (LDS 39936
// -> 4 blocks/CU; conflict-count proven identical to 560 in r9d), PROJ
// gathers stay r8-plain. prep_k/node_k unchanged.

typedef __attribute__((ext_vector_type(8))) short short8;  // 8 x bf16 (4 VGPRs)
typedef __attribute__((ext_vector_type(4))) float f32x4;   // MFMA accumulator

#define TWO_PI 6.283185307179586f
#define E_AB_TOT 131072

// ws layout (bytes)
#define WS_RT    0         // frames: 1024 x 12 f32            = 49152
#define WS_W1F   573440    // swizzled W1' 19*16*64*8 bf16     = 311296
#define WS_W2F   884736    // swizzled W2  8*8*64*8 bf16       = 65536
#define WS_PS    950272    // PROJ_S f32 1024x256 (+bias1)     = 1048576
#define WS_PD    1998848   // PROJ_D f32 1024x256              = 1048576
#define WS_W1RF  3047424   // swizzled W1_rep 9*16*64*8 bf16   = 147456
#define WS_W2RF  3194880   // swizzled W2_rep 8*16*64*8 bf16   = 131072

__device__ __forceinline__ unsigned short f2bf(float x){
  unsigned int u = __float_as_uint(x);
  u += 0x7fffu + ((u >> 16) & 1u);            // RTNE
  return (unsigned short)(u >> 16);
}

// pack two f32 -> two bf16 (RTNE) in one u32 via v_perm
__device__ __forceinline__ unsigned int pack_bf16(float lo, float hi){
  unsigned int ul = __float_as_uint(lo), uh = __float_as_uint(hi);
  ul += 0x7fffu + ((ul >> 16) & 1u);
  uh += 0x7fffu + ((uh >> 16) & 1u);
  return __builtin_amdgcn_perm(uh, ul, 0x07060302);  // {uh[31:16], ul[31:16]}
}

// gelu tanh-form == x * sigmoid(2z), z = 0.79788456(x + 0.044715 x^3)
__device__ __forceinline__ float gelu_s(float x){
  float s = x * x;
  float w = x * __builtin_fmaf(-0.1029437f, s, -2.30220847f);
  float e = __builtin_exp2f(w);
  return x * __builtin_amdgcn_rcpf(1.0f + e);
}

// ---------- prep: frames (0-3) | swz2 (4-19) | swz1 s>=1 (20-91) |
//            wg1+s0 (92-107) | swz w1r (108-143) | swz w2r (144-175) --------
__global__ __launch_bounds__(256) void prep_k(
    const float* __restrict__ coords, float* __restrict__ RT,
    const float* __restrict__ wg, const float* __restrict__ w1e,
    unsigned short* __restrict__ w1f,
    const float* __restrict__ w2e, unsigned short* __restrict__ w2f,
    const float* __restrict__ w1r, unsigned short* __restrict__ w1rf,
    const float* __restrict__ w2r, unsigned short* __restrict__ w2rf){
  __shared__ float xt[288 * 12];   // wg1 blocks: 128x16 input slab
  __shared__ float ht[256 * 12];   // wg1 blocks: 27x16 result
  int blk = blockIdx.x, tid = threadIdx.x;
  if (blk < 4){                     // ---- frames ----
    int n = blk * 256 + tid;
    const float* p = coords + n * 9;
    float ax=p[0],ay=p[1],az=p[2], bx=p[3],by=p[4],bz=p[5], cx=p[6],cy=p[7],cz=p[8];
    float v1x=cx-bx, v1y=cy-by, v1z=cz-bz;
    float v2x=ax-bx, v2y=ay-by, v2z=az-bz;
    float n1 = sqrtf(v1x*v1x+v1y*v1y+v1z*v1z) + 1e-6f;
    float e1x=v1x/n1, e1y=v1y/n1, e1z=v1z/n1;
    float dp = e1x*v2x + e1y*v2y + e1z*v2z;
    float u2x=v2x-e1x*dp, u2y=v2y-e1y*dp, u2z=v2z-e1z*dp;
    float n2 = sqrtf(u2x*u2x+u2y*u2y+u2z*u2z) + 1e-6f;
    float e2x=u2x/n2, e2y=u2y/n2, e2z=u2z/n2;
    float* r = RT + n * 12;
    r[0]=e1x; r[1]=e2x; r[2]=e1y*e2z - e1z*e2y;
    r[3]=e1y; r[4]=e2y; r[5]=e1z*e2x - e1x*e2z;
    r[6]=e1z; r[7]=e2z; r[8]=e1x*e2y - e1y*e2x;
    r[9]=bx;  r[10]=by; r[11]=bz;
  } else if (blk < 20){             // ---- swz2: W2 edge (256x128) -> frag ----
    int u = (blk - 4) * 4 + (tid >> 6);     // 0..63
    int lane = tid & 63;
    int s = u >> 3, c = u & 7;
    int n  = c * 16 + (lane & 15);
    int kb = s * 32 + (lane >> 4) * 8;
    unsigned short* o = w2f + (((s * 8 + c) * 64) + lane) * 8;
    unsigned short vals[8];
    #pragma unroll
    for (int j = 0; j < 8; ++j)
      vals[j] = f2bf(w2e[(kb + j) * 128 + n]);
    *(uint4*)o = *(const uint4*)vals;
  } else if (blk < 92){             // ---- swz1: W1' edge k-tiles s>=1 ----
    // K: [0:27 geom (wg1 blocks) | 27:91 rope (w1e 128:192) | 91:96 zero
    //     | 96:352 rep_src (192:448) | 352:608 rep_dst (448:704)]
    int u = 16 + (blk - 20) * 4 + (tid >> 6);    // 16..303 (s >= 1)
    int lane = tid & 63;
    int s = u >> 4, c = u & 15;
    int n  = c * 16 + (lane & 15);
    int kb = s * 32 + (lane >> 4) * 8;
    unsigned short* o = w1f + (((s * 16 + c) * 64) + lane) * 8;
    unsigned short vals[8];
    for (int j = 0; j < 8; ++j){
      int k = kb + j;            // >= 32 here
      float val;
      if (k < 91)       val = w1e[(128 + k - 27)  * 256 + n];
      else if (k < 96)  val = 0.f;
      else if (k < 352) val = w1e[(192 + k - 96)  * 256 + n];
      else              val = w1e[(448 + k - 352) * 256 + n];
      vals[j] = f2bf(val);
    }
    *(uint4*)o = *(const uint4*)vals;
  } else if (blk < 108){            // ---- wg1 (27x16 window) + w1f s0 tile ----
    int c = blk - 92;               // 0..15 = n-window = s0 tile index
    int n0 = c * 16;
    float* slab = xt;               // 128 x 16 f32 input slab
    float* res  = ht;               // 27 x 16 f32 result
    #pragma unroll
    for (int i = 0; i < 8; ++i){
      int idx = tid + 256 * i;      // idx = r*16 + cc
      slab[idx] = w1e[(idx >> 4) * 256 + n0 + (idx & 15)];
    }
    __syncthreads();
    #pragma unroll
    for (int i = 0; i < 2; ++i){
      int o = tid + 256 * i;        // 432 outputs = 27k x 16n
      if (o < 432){
        int k = o >> 4, cc = o & 15;
        float acc = 0.f;
        for (int j2 = 0; j2 < 128; ++j2)
          acc += wg[k * 128 + j2] * slab[j2 * 16 + cc];
        res[o] = acc;
      }
    }
    __syncthreads();
    if (tid < 64){                  // write w1f s=0 tile c (k<27 geom,
      int lane = tid;               //  k in [27,32) = first 5 rope rows)
      int nn = lane & 15;
      int kb = (lane >> 4) * 8;
      unsigned short vals[8];
      #pragma unroll
      for (int j = 0; j < 8; ++j){
        int k = kb + j;
        float val = (k < 27) ? res[k * 16 + nn]
                             : w1e[(128 + k - 27) * 256 + n0 + nn];
        vals[j] = f2bf(val);
      }
      *(uint4*)(w1f + ((c * 64) + lane) * 8) = *(const uint4*)vals;
    }
  } else if (blk < 144){            // ---- swz w1r (288x256) -> frag ----
    int u = (blk - 108) * 4 + (tid >> 6);   // 0..143: s = u>>4 (0..8), c = u&15
    int lane = tid & 63;
    int s = u >> 4, c = u & 15;
    int n  = c * 16 + (lane & 15);
    int kb = s * 32 + (lane >> 4) * 8;
    unsigned short* o = w1rf + (((s * 16 + c) * 64) + lane) * 8;
    unsigned short vals[8];
    #pragma unroll
    for (int j = 0; j < 8; ++j)
      vals[j] = f2bf(w1r[(kb + j) * 256 + n]);
    *(uint4*)o = *(const uint4*)vals;
  } else {                          // ---- swz w2r (256x256) -> frag ----
    int u = (blk - 144) * 4 + (tid >> 6);   // 0..127: s = u>>4 (0..7), c = u&15
    int lane = tid & 63;
    int s = u >> 4, c = u & 15;
    int n  = c * 16 + (lane & 15);
    int kb = s * 32 + (lane >> 4) * 8;
    unsigned short* o = w2rf + (((s * 16 + c) * 64) + lane) * 8;
    unsigned short vals[8];
    #pragma unroll
    for (int j = 0; j < 8; ++j)
      vals[j] = f2bf(w2r[(kb + j) * 256 + n]);
    *(uint4*)o = *(const uint4*)vals;
  }
}

// ---------- node_k: fused node MLP + PROJ_S/PROJ_D. 16 nodes/block, 64 blk.
// X[16 x 288] bf16 (stride 592B, 2-way = free) -> GEMM1 K=288 -> gelu ->
// H1[16 x 256] bf16 (512B + XOR swz) -> GEMM2 K=256 -> +b2+emb -> REP bf16
// in LDS (aliases X; 512B + XOR) -> PS/PD GEMMs (w1f k-tiles 3..18) ->
// global PS (+bias1) / PD. REPB global round-trip eliminated.
__global__ __launch_bounds__(512) void node_k(
    const float* __restrict__ emb, const float* __restrict__ ts,
    const float* __restrict__ tf,
    const unsigned short* __restrict__ w1rf, const float* __restrict__ b1r,
    const unsigned short* __restrict__ w2rf, const float* __restrict__ b2r,
    const unsigned short* __restrict__ w1f, const float* __restrict__ b1e,
    float* __restrict__ ps, float* __restrict__ pd)
{
  __shared__ __align__(16) char X[16 * 592];    // 9472 B; REP aliases [16*512]
  __shared__ __align__(16) char H1[16 * 512];   // 8192 B
  int tid = threadIdx.x;
  int n0g = blockIdx.x * 16;

  // ---- fill X: emb cols 0..255 ----
  #pragma unroll
  for (int i = 0; i < 2; ++i){
    int idx = tid + 512 * i;        // 1024 = 16 rows x 64 col-groups
    int row = idx >> 6, g = idx & 63;
    f32x4 e = *(const f32x4*)(emb + (n0g + row) * 256 + g * 4);
    uint2 p; p.x = pack_bf16(e[0], e[1]); p.y = pack_bf16(e[2], e[3]);
    *(uint2*)(X + row * 592 + g * 8) = p;
  }
  if (tid < 256){                   // te cols 256..287: sin at 256+j, cos 272+j
    int nd = tid >> 4, j = tid & 15;
    float ang = TWO_PI * ts[n0g + nd] * tf[j];
    float s, c; __sincosf(ang, &s, &c);
    *(unsigned short*)(X + nd * 592 + 512 + 2 * j) = f2bf(s);
    *(unsigned short*)(X + nd * 592 + 544 + 2 * j) = f2bf(c);
  }
  __syncthreads();

  int w = tid >> 6, lane = tid & 63;
  int c0 = w * 2, lr = lane & 15, quad = lane >> 4, qoff = quad * 16;
  int hx = (lr & 7) << 4;

  // ---- MLP GEMM1: D[n][node] = W1r^T x X^T, K=288 (9 k-tiles) ----
  f32x4 acc[2];
  acc[0] = (f32x4){0.f,0.f,0.f,0.f}; acc[1] = (f32x4){0.f,0.f,0.f,0.f};
  const short8* w1rf8 = (const short8*)w1rf;
  #pragma unroll
  for (int s = 0; s < 9; ++s){
    short8 a0 = w1rf8[(s * 16 + c0 + 0) * 64 + lane];
    short8 a1 = w1rf8[(s * 16 + c0 + 1) * 64 + lane];
    short8 b  = *(const short8*)(X + lr * 592 + s * 64 + qoff);
    acc[0] = __builtin_amdgcn_mfma_f32_16x16x32_bf16(a0, b, acc[0], 0, 0, 0);
    acc[1] = __builtin_amdgcn_mfma_f32_16x16x32_bf16(a1, b, acc[1], 0, 0, 0);
  }
  // H1[node][n] = gelu(D + b1r[n])
  #pragma unroll
  for (int c = 0; c < 2; ++c){
    int n = (c0 + c) * 16 + quad * 4;
    f32x4 bz = *(const f32x4*)(b1r + n);
    f32x4 s4 = acc[c];
    float v0 = gelu_s(s4[0] + bz[0]);
    float v1 = gelu_s(s4[1] + bz[1]);
    float v2 = gelu_s(s4[2] + bz[2]);
    float v3 = gelu_s(s4[3] + bz[3]);
    uint2 p; p.x = pack_bf16(v0, v1); p.y = pack_bf16(v2, v3);
    *(uint2*)(H1 + ((lr * 512 + n * 2) ^ hx)) = p;
  }
  __syncthreads();

  // ---- MLP GEMM2: D[n][node] = W2r^T x H1^T, K=256 (8 k-tiles) ----
  f32x4 acc2[2];
  acc2[0] = (f32x4){0.f,0.f,0.f,0.f}; acc2[1] = (f32x4){0.f,0.f,0.f,0.f};
  const short8* w2rf8 = (const short8*)w2rf;
  #pragma unroll
  for (int s = 0; s < 8; ++s){
    short8 a0 = w2rf8[(s * 16 + c0 + 0) * 64 + lane];
    short8 a1 = w2rf8[(s * 16 + c0 + 1) * 64 + lane];
    short8 b  = *(const short8*)(H1 + ((lr * 512 + s * 64 + qoff) ^ hx));
    acc2[0] = __builtin_amdgcn_mfma_f32_16x16x32_bf16(a0, b, acc2[0], 0, 0, 0);
    acc2[1] = __builtin_amdgcn_mfma_f32_16x16x32_bf16(a1, b, acc2[1], 0, 0, 0);
  }
  // REP[node][n] = bf16(D + b2r[n] + emb[node][n])  (REP aliases X; X dead)
  char* REP = X;
  #pragma unroll
  for (int c = 0; c < 2; ++c){
    int n = (c0 + c) * 16 + quad * 4;
    f32x4 bz = *(const f32x4*)(b2r + n);
    f32x4 e = *(const f32x4*)(emb + (n0g + lr) * 256 + n);
    f32x4 s4 = acc2[c];
    uint2 p;
    p.x = pack_bf16(s4[0] + bz[0] + e[0], s4[1] + bz[1] + e[1]);
    p.y = pack_bf16(s4[2] + bz[2] + e[2], s4[3] + bz[3] + e[3]);
    *(uint2*)(REP + ((lr * 512 + n * 2) ^ hx)) = p;
  }
  __syncthreads();

  // ---- PROJ: PS = REP @ W1_src (+b1e), PD = REP @ W1_dst; K=256 ----
  f32x4 accS[2], accD[2];
  accS[0] = (f32x4){0.f,0.f,0.f,0.f}; accS[1] = (f32x4){0.f,0.f,0.f,0.f};
  accD[0] = (f32x4){0.f,0.f,0.f,0.f}; accD[1] = (f32x4){0.f,0.f,0.f,0.f};
  const short8* w1f8 = (const short8*)w1f;
  #pragma unroll
  for (int s = 0; s < 8; ++s){
    short8 aS0 = w1f8[((3 + s) * 16 + c0 + 0) * 64 + lane];
    short8 aS1 = w1f8[((3 + s) * 16 + c0 + 1) * 64 + lane];
    short8 aD0 = w1f8[((11 + s) * 16 + c0 + 0) * 64 + lane];
    short8 aD1 = w1f8[((11 + s) * 16 + c0 + 1) * 64 + lane];
    short8 b   = *(const short8*)(REP + ((lr * 512 + s * 64 + qoff) ^ hx));
    accS[0] = __builtin_amdgcn_mfma_f32_16x16x32_bf16(aS0, b, accS[0], 0, 0, 0);
    accS[1] = __builtin_amdgcn_mfma_f32_16x16x32_bf16(aS1, b, accS[1], 0, 0, 0);
    accD[0] = __builtin_amdgcn_mfma_f32_16x16x32_bf16(aD0, b, accD[0], 0, 0, 0);
    accD[1] = __builtin_amdgcn_mfma_f32_16x16x32_bf16(aD1, b, accD[1], 0, 0, 0);
  }
  #pragma unroll
  for (int c = 0; c < 2; ++c){
    int n = (c0 + c) * 16 + quad * 4;
    f32x4 bz = *(const f32x4*)(b1e + n);
    f32x4 vS = accS[c], vD = accD[c];
    vS[0] += bz[0]; vS[1] += bz[1]; vS[2] += bz[2]; vS[3] += bz[3];
    *(f32x4*)(ps + (size_t)(n0g + lr) * 256 + n) = vS;
    *(f32x4*)(pd + (size_t)(n0g + lr) * 256 + n) = vD;
  }
}

// ---------- fused edge kernel: r8 body, H 512B+XOR (LDS 39936 -> 4 blk/CU),
// GEMM2 4n x 1e (full 256-B output spans per wave; fixes r9d write thrash) --
__global__ __launch_bounds__(512, 4) void edge_k(
    const float* __restrict__ RT,  const float* __restrict__ cf,
    const int* __restrict__ resi, const int* __restrict__ chain,
    const int* __restrict__ gia,  const int* __restrict__ gib,
    const int* __restrict__ pid,
    const unsigned short* __restrict__ w1f, const unsigned short* __restrict__ w2f,
    const float* __restrict__ ps, const float* __restrict__ pd,
    const float* __restrict__ bias2,
    float* __restrict__ outp)
{
  // phase1: edge_in 64 x 208 B (96 bf16 + pad); phase2 alias: H 64 x 512 B swz
  __shared__ __align__(16) char smem[32768];
  __shared__ __align__(16) float rtbuf[128][12];   // 64 src rows, 64 dst rows
  __shared__ float scD[64];                         // disp
  __shared__ float scI[64];                         // rope scale (chain mask)
  __shared__ int lsrc[64];
  __shared__ int ldst[64];

  int tid = threadIdx.x;
  int e0  = blockIdx.x * 64;

  if (tid < 64){                    // indices + per-edge scalars
    int e = e0 + tid, s_, d_;
    if (e < E_AB_TOT){ s_ = gia[e]; d_ = gib[e]; }
    else {
      int i = e - E_AB_TOT;
      int b = i >> 10, w_ = i & 1023;
      s_ = pid[b * 32 + (w_ >> 5)];
      d_ = pid[b * 32 + (w_ & 31)];
    }
    lsrc[tid] = s_; ldst[tid] = d_;
    float disp = ((float)resi[s_] - (float)resi[d_]) * 0.125f;
    scD[tid] = disp;
    scI[tid] = (chain[s_] == chain[d_]) ? 1.f / (fabsf(disp) + 1.f) : 0.f;
  } else if (tid < 192){            // RT staging: 128 rows x 48 B, vectorized
    int r  = tid - 64;              // 0..127 : 0..63 = src rows, 64..127 = dst
    int e  = e0 + (r & 63);
    int node;
    if (e < E_AB_TOT){ node = (r < 64) ? gia[e] : gib[e]; }
    else {
      int i = e - E_AB_TOT;
      int b = i >> 10, w_ = i & 1023;
      node = (r < 64) ? pid[b * 32 + (w_ >> 5)] : pid[b * 32 + (w_ & 31)];
    }
    const f32x4* p = (const f32x4*)(RT + node * 12);
    f32x4* q = (f32x4*)(&rtbuf[r][0]);
    q[0] = p[0]; q[1] = p[1]; q[2] = p[2];
  }
  __syncthreads();

  // ---- divergence-free feature fill (cols 0..95 of edge_in) ----
  {
    // rope: 2048 (edge, freq) pairs, one sincos fills sin+cos cols
    #pragma unroll
    for (int it = 0; it < 4; ++it){
      int v = it * 512 + tid, ed = v >> 5, j = v & 31;
      float ang = TWO_PI * scD[ed] * cf[j];
      float s, c; __sincosf(ang, &s, &c);
      float inv = scI[ed];
      unsigned short* row = (unsigned short*)(smem + ed * 208);
      row[27 + j] = f2bf(s * inv);
      row[59 + j] = f2bf(c * inv);
    }
    // rbf: 64 edges x 15 centers (c==15 lanes idle)
    #pragma unroll
    for (int it = 0; it < 2; ++it){
      int v = it * 512 + tid, ed = v >> 4, c = v & 15;
      float tx = rtbuf[64 + ed][9]  - rtbuf[ed][9];
      float ty = rtbuf[64 + ed][10] - rtbuf[ed][10];
      float tz = rtbuf[64 + ed][11] - rtbuf[ed][11];
      float dist = sqrtf(tx*tx + ty*ty + tz*tz + 1e-6f);
      if (c < 15){
        float z = (dist - (float)c * (20.f / 14.f)) * (15.f / 20.f);
        ((unsigned short*)(smem + ed * 208))[c] = f2bf(__expf(-0.5f * z * z));
      }
    }
    // relrot (9) + local (3): cols 15..26
    #pragma unroll
    for (int it = 0; it < 2; ++it){
      int v = it * 512 + tid, ed = v >> 4, cc = v & 15;
      if (cc < 12){
        const float* Rs = &rtbuf[ed][0];
        const float* Rd = &rtbuf[64 + ed][0];
        float val;
        if (cc < 9){
          int a  = (cc >= 6) ? 2 : ((cc >= 3) ? 1 : 0);
          int b_ = cc - 3 * a;
          val = Rs[a]*Rd[b_] + Rs[3+a]*Rd[3+b_] + Rs[6+a]*Rd[6+b_];
        } else {
          int k = cc - 9;
          float tx = Rd[9]-Rs[9], ty = Rd[10]-Rs[10], tz = Rd[11]-Rs[11];
          float dist = sqrtf(tx*tx + ty*ty + tz*tz + 1e-6f);
          val = (Rs[k]*tx + Rs[3+k]*ty + Rs[6+k]*tz) / (dist + 1.f);
        }
        ((unsigned short*)(smem + ed * 208))[15 + cc] = f2bf(val);
      }
    }
    // zeros: cols 91..98 (96..98 are pad, harmless)
    {
      int ed = tid >> 3, c8 = tid & 7;
      ((unsigned short*)(smem + ed * 208))[91 + c8] = 0;
    }
  }
  __syncthreads();

  // ---- GEMM1 (transposed): D[n][e] = W1_feat^T x edge_in^T, K=96 ----
  int w    = tid >> 6, lane = tid & 63;
  int c0   = w * 2;                 // 2 n-tiles per wave
  int lr   = lane & 15;             // edge within e-tile
  int quad = lane >> 4, qoff = quad * 16;
  f32x4 acc[8];                     // [c*4 + etile]
  #pragma unroll
  for (int i = 0; i < 8; ++i) acc[i] = (f32x4){0.f, 0.f, 0.f, 0.f};
  const short8* w1f8 = (const short8*)w1f;

  #pragma unroll
  for (int s = 0; s < 3; ++s){
    short8 a0 = w1f8[(s * 16 + c0 + 0) * 64 + lane];
    short8 a1 = w1f8[(s * 16 + c0 + 1) * 64 + lane];
    short8 be0 = *(const short8*)(smem + ( 0 + lr) * 208 + s * 64 + qoff);
    short8 be1 = *(const short8*)(smem + (16 + lr) * 208 + s * 64 + qoff);
    short8 be2 = *(const short8*)(smem + (32 + lr) * 208 + s * 64 + qoff);
    short8 be3 = *(const short8*)(smem + (48 + lr) * 208 + s * 64 + qoff);
    acc[0] = __builtin_amdgcn_mfma_f32_16x16x32_bf16(a0, be0, acc[0], 0, 0, 0);
    acc[1] = __builtin_amdgcn_mfma_f32_16x16x32_bf16(a0, be1, acc[1], 0, 0, 0);
    acc[2] = __builtin_amdgcn_mfma_f32_16x16x32_bf16(a0, be2, acc[2], 0, 0, 0);
    acc[3] = __builtin_amdgcn_mfma_f32_16x16x32_bf16(a0, be3, acc[3], 0, 0, 0);
    acc[4] = __builtin_amdgcn_mfma_f32_16x16x32_bf16(a1, be0, acc[4], 0, 0, 0);
    acc[5] = __builtin_amdgcn_mfma_f32_16x16x32_bf16(a1, be1, acc[5], 0, 0, 0);
    acc[6] = __builtin_amdgcn_mfma_f32_16x16x32_bf16(a1, be2, acc[6], 0, 0, 0);
    acc[7] = __builtin_amdgcn_mfma_f32_16x16x32_bf16(a1, be3, acc[7], 0, 0, 0);
  }
  __syncthreads();   // edge_in reads done; alias LDS as H (64 x 512 B, swz)

  // H[e][n] = gelu(D + PROJ_S[src][n] + PROJ_D[dst][n])   (b1 inside PROJ_S)
  {
    char* Hb = smem;
    #pragma unroll
    for (int c = 0; c < 2; ++c){
      int n = (c0 + c) * 16 + quad * 4;
      f32x4 pv[4], qv[4];
      #pragma unroll
      for (int t = 0; t < 4; ++t){
        pv[t] = *(const f32x4*)(ps + (size_t)lsrc[t * 16 + lr] * 256 + n);
        qv[t] = *(const f32x4*)(pd + (size_t)ldst[t * 16 + lr] * 256 + n);
      }
      #pragma unroll
      for (int t = 0; t < 4; ++t){
        int e = t * 16 + lr;
        f32x4 s4 = acc[c * 4 + t];
        float v0 = gelu_s(s4[0] + pv[t][0] + qv[t][0]);
        float v1 = gelu_s(s4[1] + pv[t][1] + qv[t][1]);
        float v2 = gelu_s(s4[2] + pv[t][2] + qv[t][2]);
        float v3 = gelu_s(s4[3] + pv[t][3] + qv[t][3]);
        uint2 p; p.x = pack_bf16(v0, v1); p.y = pack_bf16(v2, v3);
        *(uint2*)(Hb + ((e * 512 + n * 2) ^ ((e & 7) << 4))) = p;
      }
    }
  }
  __syncthreads();

  // ---- GEMM2 (transposed): wave owns n-tiles {c2..c2+3} x e-tile eb ------
  // 4n x 1e: each wave writes the FULL 256-B span [c2*64, c2*64+256) of its
  // 16 edge rows -> no cross-wave 256-B line sharing (r9d thrash fix).
  int c2 = (w & 1) * 4;
  int eb = (w >> 1) * 16;
  int hx = (lr & 7) << 4;           // rows differ by 16 -> row&7 == lr&7
  f32x4 acc2[4];                    // [j] = n-tile c2+j
  #pragma unroll
  for (int i = 0; i < 4; ++i) acc2[i] = (f32x4){0.f, 0.f, 0.f, 0.f};
  const short8* w2f8 = (const short8*)w2f;
  #pragma unroll
  for (int s = 0; s < 8; ++s){
    short8 aa0 = w2f8[(s * 8 + c2 + 0) * 64 + lane];
    short8 aa1 = w2f8[(s * 8 + c2 + 1) * 64 + lane];
    short8 aa2 = w2f8[(s * 8 + c2 + 2) * 64 + lane];
    short8 aa3 = w2f8[(s * 8 + c2 + 3) * 64 + lane];
    short8 h = *(const short8*)(smem + (((eb + lr) * 512 + s * 64 + qoff) ^ hx));
    acc2[0] = __builtin_amdgcn_mfma_f32_16x16x32_bf16(aa0, h, acc2[0], 0, 0, 0);
    acc2[1] = __builtin_amdgcn_mfma_f32_16x16x32_bf16(aa1, h, acc2[1], 0, 0, 0);
    acc2[2] = __builtin_amdgcn_mfma_f32_16x16x32_bf16(aa2, h, acc2[2], 0, 0, 0);
    acc2[3] = __builtin_amdgcn_mfma_f32_16x16x32_bf16(aa3, h, acc2[3], 0, 0, 0);
  }

  // output: lane writes 4 x f32x4 for edge eb+lr at n = (c2+j)*16 + quad*4
  {
    float* og = outp + (size_t)(e0 + eb + lr) * 128;
    #pragma unroll
    for (int j = 0; j < 4; ++j){
      int n = (c2 + j) * 16 + quad * 4;
      f32x4 bz = *(const f32x4*)(bias2 + n);
      f32x4 v = acc2[j];
      v[0] += bz[0]; v[1] += bz[1]; v[2] += bz[2]; v[3] += bz[3];
      *(f32x4*)(og + n) = v;
    }
  }
}

extern "C" void kernel_launch(void* const* d_in, const int* in_sizes, int n_in,
                              void* d_out, int out_size, void* d_ws, size_t ws_size,
                              hipStream_t stream) {
  const float* emb    = (const float*)d_in[0];
  const float* ts     = (const float*)d_in[1];
  const float* coords = (const float*)d_in[2];
  const float* tf     = (const float*)d_in[3];
  const float* cf     = (const float*)d_in[4];
  const float* w1r    = (const float*)d_in[5];
  const float* b1r    = (const float*)d_in[6];
  const float* w2r    = (const float*)d_in[7];
  const float* b2r    = (const float*)d_in[8];
  const float* wg     = (const float*)d_in[9];
  const float* w1e    = (const float*)d_in[10];
  const float* b1e    = (const float*)d_in[11];
  const float* w2e    = (const float*)d_in[12];
  const float* b2e    = (const float*)d_in[13];
  const int* resi     = (const int*)d_in[14];
  const int* chain    = (const int*)d_in[15];
  const int* gia      = (const int*)d_in[16];
  const int* gib      = (const int*)d_in[17];
  const int* pid      = (const int*)d_in[18];

  char* ws = (char*)d_ws;
  float* RT            = (float*)(ws + WS_RT);
  unsigned short* W1F  = (unsigned short*)(ws + WS_W1F);
  unsigned short* W2F  = (unsigned short*)(ws + WS_W2F);
  float* PS            = (float*)(ws + WS_PS);
  float* PD            = (float*)(ws + WS_PD);
  unsigned short* W1RF = (unsigned short*)(ws + WS_W1RF);
  unsigned short* W2RF = (unsigned short*)(ws + WS_W2RF);
  float* outp          = (float*)d_out;

  hipLaunchKernelGGL(prep_k, dim3(176), dim3(256), 0, stream,
                     coords, RT, wg, w1e, W1F, w2e, W2F, w1r, W1RF, w2r, W2RF);
  hipLaunchKernelGGL(node_k, dim3(64), dim3(512), 0, stream,
                     emb, ts, tf, W1RF, b1r, W2RF, b2r, W1F, b1e, PS, PD);
  hipLaunchKernelGGL(edge_k, dim3(2080), dim3(512), 0, stream,
                     RT, cf, resi, chain, gia, gib, pid, W1F, W2F, PS, PD,
                     b2e, outp);
}

// Round 15
// 181.677 us; speedup vs baseline: 1.0381x; 1.0381x over previous
//
#include <hip/hip_runtime.h>

// BindingFormer fused pipeline for MI355X (gfx950), round 16 = r14b restore.
// r15 post-mortem: 4n x 1e GEMM2 remap REGRESSED (72.2 -> 76.7): conflicts
// fell 2.43M->1.90M but LDS-read count rose (40 vs 32 ds_reads/wave) ->
// conflicts were never the GEMM2 lever. Occupancy never moved at (512,4)
// (launch-bounds arg, not LDS, gated residency in r9d). Ledger: r8 edge
// body = optimum of 7 variants; all session wins came from DELETING work
// (PROJ factorization r7, MFMA MLP r13, node fusion r14). Final config =
// measured best: prep_k + fused node_k + r8-body edge_k (182.0 us).

typedef __attribute__((ext_vector_type(8))) short short8;  // 8 x bf16 (4 VGPRs)
typedef __attribute__((ext_vector_type(4))) float f32x4;   // MFMA accumulator

#define TWO_PI 6.283185307179586f
#define E_AB_TOT 131072

// ws layout (bytes)
#define WS_RT    0         // frames: 1024 x 12 f32            = 49152
#define WS_W1F   573440    // swizzled W1' 19*16*64*8 bf16     = 311296
#define WS_W2F   884736    // swizzled W2  8*8*64*8 bf16       = 65536
#define WS_PS    950272    // PROJ_S f32 1024x256 (+bias1)     = 1048576
#define WS_PD    1998848   // PROJ_D f32 1024x256              = 1048576
#define WS_W1RF  3047424   // swizzled W1_rep 9*16*64*8 bf16   = 147456
#define WS_W2RF  3194880   // swizzled W2_rep 8*16*64*8 bf16   = 131072

__device__ __forceinline__ unsigned short f2bf(float x){
  unsigned int u = __float_as_uint(x);
  u += 0x7fffu + ((u >> 16) & 1u);            // RTNE
  return (unsigned short)(u >> 16);
}

// pack two f32 -> two bf16 (RTNE) in one u32 via v_perm
__device__ __forceinline__ unsigned int pack_bf16(float lo, float hi){
  unsigned int ul = __float_as_uint(lo), uh = __float_as_uint(hi);
  ul += 0x7fffu + ((ul >> 16) & 1u);
  uh += 0x7fffu + ((uh >> 16) & 1u);
  return __builtin_amdgcn_perm(uh, ul, 0x07060302);  // {uh[31:16], ul[31:16]}
}

// gelu tanh-form == x * sigmoid(2z), z = 0.79788456(x + 0.044715 x^3)
__device__ __forceinline__ float gelu_s(float x){
  float s = x * x;
  float w = x * __builtin_fmaf(-0.1029437f, s, -2.30220847f);
  float e = __builtin_exp2f(w);
  return x * __builtin_amdgcn_rcpf(1.0f + e);
}

// ---------- prep: frames (0-3) | swz2 (4-19) | swz1 s>=1 (20-91) |
//            wg1+s0 (92-107) | swz w1r (108-143) | swz w2r (144-175) --------
__global__ __launch_bounds__(256) void prep_k(
    const float* __restrict__ coords, float* __restrict__ RT,
    const float* __restrict__ wg, const float* __restrict__ w1e,
    unsigned short* __restrict__ w1f,
    const float* __restrict__ w2e, unsigned short* __restrict__ w2f,
    const float* __restrict__ w1r, unsigned short* __restrict__ w1rf,
    const float* __restrict__ w2r, unsigned short* __restrict__ w2rf){
  __shared__ float xt[288 * 12];   // wg1 blocks: 128x16 input slab
  __shared__ float ht[256 * 12];   // wg1 blocks: 27x16 result
  int blk = blockIdx.x, tid = threadIdx.x;
  if (blk < 4){                     // ---- frames ----
    int n = blk * 256 + tid;
    const float* p = coords + n * 9;
    float ax=p[0],ay=p[1],az=p[2], bx=p[3],by=p[4],bz=p[5], cx=p[6],cy=p[7],cz=p[8];
    float v1x=cx-bx, v1y=cy-by, v1z=cz-bz;
    float v2x=ax-bx, v2y=ay-by, v2z=az-bz;
    float n1 = sqrtf(v1x*v1x+v1y*v1y+v1z*v1z) + 1e-6f;
    float e1x=v1x/n1, e1y=v1y/n1, e1z=v1z/n1;
    float dp = e1x*v2x + e1y*v2y + e1z*v2z;
    float u2x=v2x-e1x*dp, u2y=v2y-e1y*dp, u2z=v2z-e1z*dp;
    float n2 = sqrtf(u2x*u2x+u2y*u2y+u2z*u2z) + 1e-6f;
    float e2x=u2x/n2, e2y=u2y/n2, e2z=u2z/n2;
    float* r = RT + n * 12;
    r[0]=e1x; r[1]=e2x; r[2]=e1y*e2z - e1z*e2y;
    r[3]=e1y; r[4]=e2y; r[5]=e1z*e2x - e1x*e2z;
    r[6]=e1z; r[7]=e2z; r[8]=e1x*e2y - e1y*e2x;
    r[9]=bx;  r[10]=by; r[11]=bz;
  } else if (blk < 20){             // ---- swz2: W2 edge (256x128) -> frag ----
    int u = (blk - 4) * 4 + (tid >> 6);     // 0..63
    int lane = tid & 63;
    int s = u >> 3, c = u & 7;
    int n  = c * 16 + (lane & 15);
    int kb = s * 32 + (lane >> 4) * 8;
    unsigned short* o = w2f + (((s * 8 + c) * 64) + lane) * 8;
    unsigned short vals[8];
    #pragma unroll
    for (int j = 0; j < 8; ++j)
      vals[j] = f2bf(w2e[(kb + j) * 128 + n]);
    *(uint4*)o = *(const uint4*)vals;
  } else if (blk < 92){             // ---- swz1: W1' edge k-tiles s>=1 ----
    // K: [0:27 geom (wg1 blocks) | 27:91 rope (w1e 128:192) | 91:96 zero
    //     | 96:352 rep_src (192:448) | 352:608 rep_dst (448:704)]
    int u = 16 + (blk - 20) * 4 + (tid >> 6);    // 16..303 (s >= 1)
    int lane = tid & 63;
    int s = u >> 4, c = u & 15;
    int n  = c * 16 + (lane & 15);
    int kb = s * 32 + (lane >> 4) * 8;
    unsigned short* o = w1f + (((s * 16 + c) * 64) + lane) * 8;
    unsigned short vals[8];
    for (int j = 0; j < 8; ++j){
      int k = kb + j;            // >= 32 here
      float val;
      if (k < 91)       val = w1e[(128 + k - 27)  * 256 + n];
      else if (k < 96)  val = 0.f;
      else if (k < 352) val = w1e[(192 + k - 96)  * 256 + n];
      else              val = w1e[(448 + k - 352) * 256 + n];
      vals[j] = f2bf(val);
    }
    *(uint4*)o = *(const uint4*)vals;
  } else if (blk < 108){            // ---- wg1 (27x16 window) + w1f s0 tile ----
    int c = blk - 92;               // 0..15 = n-window = s0 tile index
    int n0 = c * 16;
    float* slab = xt;               // 128 x 16 f32 input slab
    float* res  = ht;               // 27 x 16 f32 result
    #pragma unroll
    for (int i = 0; i < 8; ++i){
      int idx = tid + 256 * i;      // idx = r*16 + cc
      slab[idx] = w1e[(idx >> 4) * 256 + n0 + (idx & 15)];
    }
    __syncthreads();
    #pragma unroll
    for (int i = 0; i < 2; ++i){
      int o = tid + 256 * i;        // 432 outputs = 27k x 16n
      if (o < 432){
        int k = o >> 4, cc = o & 15;
        float acc = 0.f;
        for (int j2 = 0; j2 < 128; ++j2)
          acc += wg[k * 128 + j2] * slab[j2 * 16 + cc];
        res[o] = acc;
      }
    }
    __syncthreads();
    if (tid < 64){                  // write w1f s=0 tile c (k<27 geom,
      int lane = tid;               //  k in [27,32) = first 5 rope rows)
      int nn = lane & 15;
      int kb = (lane >> 4) * 8;
      unsigned short vals[8];
      #pragma unroll
      for (int j = 0; j < 8; ++j){
        int k = kb + j;
        float val = (k < 27) ? res[k * 16 + nn]
                             : w1e[(128 + k - 27) * 256 + n0 + nn];
        vals[j] = f2bf(val);
      }
      *(uint4*)(w1f + ((c * 64) + lane) * 8) = *(const uint4*)vals;
    }
  } else if (blk < 144){            // ---- swz w1r (288x256) -> frag ----
    int u = (blk - 108) * 4 + (tid >> 6);   // 0..143: s = u>>4 (0..8), c = u&15
    int lane = tid & 63;
    int s = u >> 4, c = u & 15;
    int n  = c * 16 + (lane & 15);
    int kb = s * 32 + (lane >> 4) * 8;
    unsigned short* o = w1rf + (((s * 16 + c) * 64) + lane) * 8;
    unsigned short vals[8];
    #pragma unroll
    for (int j = 0; j < 8; ++j)
      vals[j] = f2bf(w1r[(kb + j) * 256 + n]);
    *(uint4*)o = *(const uint4*)vals;
  } else {                          // ---- swz w2r (256x256) -> frag ----
    int u = (blk - 144) * 4 + (tid >> 6);   // 0..127: s = u>>4 (0..7), c = u&15
    int lane = tid & 63;
    int s = u >> 4, c = u & 15;
    int n  = c * 16 + (lane & 15);
    int kb = s * 32 + (lane >> 4) * 8;
    unsigned short* o = w2rf + (((s * 16 + c) * 64) + lane) * 8;
    unsigned short vals[8];
    #pragma unroll
    for (int j = 0; j < 8; ++j)
      vals[j] = f2bf(w2r[(kb + j) * 256 + n]);
    *(uint4*)o = *(const uint4*)vals;
  }
}

// ---------- node_k: fused node MLP + PROJ_S/PROJ_D. 16 nodes/block, 64 blk.
// X[16 x 288] bf16 (stride 592B, 2-way = free) -> GEMM1 K=288 -> gelu ->
// H1[16 x 256] bf16 (512B + XOR swz) -> GEMM2 K=256 -> +b2+emb -> REP bf16
// in LDS (aliases X; 512B + XOR) -> PS/PD GEMMs (w1f k-tiles 3..18) ->
// global PS (+bias1) / PD. REPB global round-trip eliminated.
__global__ __launch_bounds__(512) void node_k(
    const float* __restrict__ emb, const float* __restrict__ ts,
    const float* __restrict__ tf,
    const unsigned short* __restrict__ w1rf, const float* __restrict__ b1r,
    const unsigned short* __restrict__ w2rf, const float* __restrict__ b2r,
    const unsigned short* __restrict__ w1f, const float* __restrict__ b1e,
    float* __restrict__ ps, float* __restrict__ pd)
{
  __shared__ __align__(16) char X[16 * 592];    // 9472 B; REP aliases [16*512]
  __shared__ __align__(16) char H1[16 * 512];   // 8192 B
  int tid = threadIdx.x;
  int n0g = blockIdx.x * 16;

  // ---- fill X: emb cols 0..255 ----
  #pragma unroll
  for (int i = 0; i < 2; ++i){
    int idx = tid + 512 * i;        // 1024 = 16 rows x 64 col-groups
    int row = idx >> 6, g = idx & 63;
    f32x4 e = *(const f32x4*)(emb + (n0g + row) * 256 + g * 4);
    uint2 p; p.x = pack_bf16(e[0], e[1]); p.y = pack_bf16(e[2], e[3]);
    *(uint2*)(X + row * 592 + g * 8) = p;
  }
  if (tid < 256){                   // te cols 256..287: sin at 256+j, cos 272+j
    int nd = tid >> 4, j = tid & 15;
    float ang = TWO_PI * ts[n0g + nd] * tf[j];
    float s, c; __sincosf(ang, &s, &c);
    *(unsigned short*)(X + nd * 592 + 512 + 2 * j) = f2bf(s);
    *(unsigned short*)(X + nd * 592 + 544 + 2 * j) = f2bf(c);
  }
  __syncthreads();

  int w = tid >> 6, lane = tid & 63;
  int c0 = w * 2, lr = lane & 15, quad = lane >> 4, qoff = quad * 16;
  int hx = (lr & 7) << 4;

  // ---- MLP GEMM1: D[n][node] = W1r^T x X^T, K=288 (9 k-tiles) ----
  f32x4 acc[2];
  acc[0] = (f32x4){0.f,0.f,0.f,0.f}; acc[1] = (f32x4){0.f,0.f,0.f,0.f};
  const short8* w1rf8 = (const short8*)w1rf;
  #pragma unroll
  for (int s = 0; s < 9; ++s){
    short8 a0 = w1rf8[(s * 16 + c0 + 0) * 64 + lane];
    short8 a1 = w1rf8[(s * 16 + c0 + 1) * 64 + lane];
    short8 b  = *(const short8*)(X + lr * 592 + s * 64 + qoff);
    acc[0] = __builtin_amdgcn_mfma_f32_16x16x32_bf16(a0, b, acc[0], 0, 0, 0);
    acc[1] = __builtin_amdgcn_mfma_f32_16x16x32_bf16(a1, b, acc[1], 0, 0, 0);
  }
  // H1[node][n] = gelu(D + b1r[n])
  #pragma unroll
  for (int c = 0; c < 2; ++c){
    int n = (c0 + c) * 16 + quad * 4;
    f32x4 bz = *(const f32x4*)(b1r + n);
    f32x4 s4 = acc[c];
    float v0 = gelu_s(s4[0] + bz[0]);
    float v1 = gelu_s(s4[1] + bz[1]);
    float v2 = gelu_s(s4[2] + bz[2]);
    float v3 = gelu_s(s4[3] + bz[3]);
    uint2 p; p.x = pack_bf16(v0, v1); p.y = pack_bf16(v2, v3);
    *(uint2*)(H1 + ((lr * 512 + n * 2) ^ hx)) = p;
  }
  __syncthreads();

  // ---- MLP GEMM2: D[n][node] = W2r^T x H1^T, K=256 (8 k-tiles) ----
  f32x4 acc2[2];
  acc2[0] = (f32x4){0.f,0.f,0.f,0.f}; acc2[1] = (f32x4){0.f,0.f,0.f,0.f};
  const short8* w2rf8 = (const short8*)w2rf;
  #pragma unroll
  for (int s = 0; s < 8; ++s){
    short8 a0 = w2rf8[(s * 16 + c0 + 0) * 64 + lane];
    short8 a1 = w2rf8[(s * 16 + c0 + 1) * 64 + lane];
    short8 b  = *(const short8*)(H1 + ((lr * 512 + s * 64 + qoff) ^ hx));
    acc2[0] = __builtin_amdgcn_mfma_f32_16x16x32_bf16(a0, b, acc2[0], 0, 0, 0);
    acc2[1] = __builtin_amdgcn_mfma_f32_16x16x32_bf16(a1, b, acc2[1], 0, 0, 0);
  }
  // REP[node][n] = bf16(D + b2r[n] + emb[node][n])  (REP aliases X; X dead)
  char* REP = X;
  #pragma unroll
  for (int c = 0; c < 2; ++c){
    int n = (c0 + c) * 16 + quad * 4;
    f32x4 bz = *(const f32x4*)(b2r + n);
    f32x4 e = *(const f32x4*)(emb + (n0g + lr) * 256 + n);
    f32x4 s4 = acc2[c];
    uint2 p;
    p.x = pack_bf16(s4[0] + bz[0] + e[0], s4[1] + bz[1] + e[1]);
    p.y = pack_bf16(s4[2] + bz[2] + e[2], s4[3] + bz[3] + e[3]);
    *(uint2*)(REP + ((lr * 512 + n * 2) ^ hx)) = p;
  }
  __syncthreads();

  // ---- PROJ: PS = REP @ W1_src (+b1e), PD = REP @ W1_dst; K=256 ----
  f32x4 accS[2], accD[2];
  accS[0] = (f32x4){0.f,0.f,0.f,0.f}; accS[1] = (f32x4){0.f,0.f,0.f,0.f};
  accD[0] = (f32x4){0.f,0.f,0.f,0.f}; accD[1] = (f32x4){0.f,0.f,0.f,0.f};
  const short8* w1f8 = (const short8*)w1f;
  #pragma unroll
  for (int s = 0; s < 8; ++s){
    short8 aS0 = w1f8[((3 + s) * 16 + c0 + 0) * 64 + lane];
    short8 aS1 = w1f8[((3 + s) * 16 + c0 + 1) * 64 + lane];
    short8 aD0 = w1f8[((11 + s) * 16 + c0 + 0) * 64 + lane];
    short8 aD1 = w1f8[((11 + s) * 16 + c0 + 1) * 64 + lane];
    short8 b   = *(const short8*)(REP + ((lr * 512 + s * 64 + qoff) ^ hx));
    accS[0] = __builtin_amdgcn_mfma_f32_16x16x32_bf16(aS0, b, accS[0], 0, 0, 0);
    accS[1] = __builtin_amdgcn_mfma_f32_16x16x32_bf16(aS1, b, accS[1], 0, 0, 0);
    accD[0] = __builtin_amdgcn_mfma_f32_16x16x32_bf16(aD0, b, accD[0], 0, 0, 0);
    accD[1] = __builtin_amdgcn_mfma_f32_16x16x32_bf16(aD1, b, accD[1], 0, 0, 0);
  }
  #pragma unroll
  for (int c = 0; c < 2; ++c){
    int n = (c0 + c) * 16 + quad * 4;
    f32x4 bz = *(const f32x4*)(b1e + n);
    f32x4 vS = accS[c], vD = accD[c];
    vS[0] += bz[0]; vS[1] += bz[1]; vS[2] += bz[2]; vS[3] += bz[3];
    *(f32x4*)(ps + (size_t)(n0g + lr) * 256 + n) = vS;
    *(f32x4*)(pd + (size_t)(n0g + lr) * 256 + n) = vD;
  }
}

// ---------- fused edge kernel (r8 body verbatim: 72.0us measured) ----------
// 64 edges/block, 512 thr; H stride 560 (conflict-free); plain PROJ gathers
// in the H epilogue; LDS 43008 -> 3 blocks/CU (clean-write regime).
__global__ __launch_bounds__(512, 4) void edge_k(
    const float* __restrict__ RT,  const float* __restrict__ cf,
    const int* __restrict__ resi, const int* __restrict__ chain,
    const int* __restrict__ gia,  const int* __restrict__ gib,
    const int* __restrict__ pid,
    const unsigned short* __restrict__ w1f, const unsigned short* __restrict__ w2f,
    const float* __restrict__ ps, const float* __restrict__ pd,
    const float* __restrict__ bias2,
    float* __restrict__ outp)
{
  // phase1: edge_in 64 x 208 B (96 bf16 + pad); phase2 alias: H 64 x 560 B
  __shared__ __align__(16) char smem[35840];
  __shared__ __align__(16) float rtbuf[128][12];   // 64 src rows, 64 dst rows
  __shared__ float scD[64];                         // disp
  __shared__ float scI[64];                         // rope scale (chain mask)
  __shared__ int lsrc[64];
  __shared__ int ldst[64];

  int tid = threadIdx.x;
  int e0  = blockIdx.x * 64;

  if (tid < 64){                    // indices + per-edge scalars
    int e = e0 + tid, s_, d_;
    if (e < E_AB_TOT){ s_ = gia[e]; d_ = gib[e]; }
    else {
      int i = e - E_AB_TOT;
      int b = i >> 10, w_ = i & 1023;
      s_ = pid[b * 32 + (w_ >> 5)];
      d_ = pid[b * 32 + (w_ & 31)];
    }
    lsrc[tid] = s_; ldst[tid] = d_;
    float disp = ((float)resi[s_] - (float)resi[d_]) * 0.125f;
    scD[tid] = disp;
    scI[tid] = (chain[s_] == chain[d_]) ? 1.f / (fabsf(disp) + 1.f) : 0.f;
  } else if (tid < 192){            // RT staging: 128 rows x 48 B, vectorized
    int r  = tid - 64;              // 0..127 : 0..63 = src rows, 64..127 = dst
    int e  = e0 + (r & 63);
    int node;
    if (e < E_AB_TOT){ node = (r < 64) ? gia[e] : gib[e]; }
    else {
      int i = e - E_AB_TOT;
      int b = i >> 10, w_ = i & 1023;
      node = (r < 64) ? pid[b * 32 + (w_ >> 5)] : pid[b * 32 + (w_ & 31)];
    }
    const f32x4* p = (const f32x4*)(RT + node * 12);
    f32x4* q = (f32x4*)(&rtbuf[r][0]);
    q[0] = p[0]; q[1] = p[1]; q[2] = p[2];
  }
  __syncthreads();

  // ---- divergence-free feature fill (cols 0..95 of edge_in) ----
  {
    // rope: 2048 (edge, freq) pairs, one sincos fills sin+cos cols
    #pragma unroll
    for (int it = 0; it < 4; ++it){
      int v = it * 512 + tid, ed = v >> 5, j = v & 31;
      float ang = TWO_PI * scD[ed] * cf[j];
      float s, c; __sincosf(ang, &s, &c);
      float inv = scI[ed];
      unsigned short* row = (unsigned short*)(smem + ed * 208);
      row[27 + j] = f2bf(s * inv);
      row[59 + j] = f2bf(c * inv);
    }
    // rbf: 64 edges x 15 centers (c==15 lanes idle)
    #pragma unroll
    for (int it = 0; it < 2; ++it){
      int v = it * 512 + tid, ed = v >> 4, c = v & 15;
      float tx = rtbuf[64 + ed][9]  - rtbuf[ed][9];
      float ty = rtbuf[64 + ed][10] - rtbuf[ed][10];
      float tz = rtbuf[64 + ed][11] - rtbuf[ed][11];
      float dist = sqrtf(tx*tx + ty*ty + tz*tz + 1e-6f);
      if (c < 15){
        float z = (dist - (float)c * (20.f / 14.f)) * (15.f / 20.f);
        ((unsigned short*)(smem + ed * 208))[c] = f2bf(__expf(-0.5f * z * z));
      }
    }
    // relrot (9) + local (3): cols 15..26
    #pragma unroll
    for (int it = 0; it < 2; ++it){
      int v = it * 512 + tid, ed = v >> 4, cc = v & 15;
      if (cc < 12){
        const float* Rs = &rtbuf[ed][0];
        const float* Rd = &rtbuf[64 + ed][0];
        float val;
        if (cc < 9){
          int a  = (cc >= 6) ? 2 : ((cc >= 3) ? 1 : 0);
          int b_ = cc - 3 * a;
          val = Rs[a]*Rd[b_] + Rs[3+a]*Rd[3+b_] + Rs[6+a]*Rd[6+b_];
        } else {
          int k = cc - 9;
          float tx = Rd[9]-Rs[9], ty = Rd[10]-Rs[10], tz = Rd[11]-Rs[11];
          float dist = sqrtf(tx*tx + ty*ty + tz*tz + 1e-6f);
          val = (Rs[k]*tx + Rs[3+k]*ty + Rs[6+k]*tz) / (dist + 1.f);
        }
        ((unsigned short*)(smem + ed * 208))[15 + cc] = f2bf(val);
      }
    }
    // zeros: cols 91..98 (96..98 are pad, harmless)
    {
      int ed = tid >> 3, c8 = tid & 7;
      ((unsigned short*)(smem + ed * 208))[91 + c8] = 0;
    }
  }
  __syncthreads();

  // ---- GEMM1 (transposed): D[n][e] = W1_feat^T x edge_in^T, K=96 ----
  int w    = tid >> 6, lane = tid & 63;
  int c0   = w * 2;                 // 2 n-tiles per wave
  int lr   = lane & 15;             // edge within e-tile
  int quad = lane >> 4, qoff = quad * 16;
  f32x4 acc[8];                     // [c*4 + etile]
  #pragma unroll
  for (int i = 0; i < 8; ++i) acc[i] = (f32x4){0.f, 0.f, 0.f, 0.f};
  const short8* w1f8 = (const short8*)w1f;

  #pragma unroll
  for (int s = 0; s < 3; ++s){
    short8 a0 = w1f8[(s * 16 + c0 + 0) * 64 + lane];
    short8 a1 = w1f8[(s * 16 + c0 + 1) * 64 + lane];
    short8 be0 = *(const short8*)(smem + ( 0 + lr) * 208 + s * 64 + qoff);
    short8 be1 = *(const short8*)(smem + (16 + lr) * 208 + s * 64 + qoff);
    short8 be2 = *(const short8*)(smem + (32 + lr) * 208 + s * 64 + qoff);
    short8 be3 = *(const short8*)(smem + (48 + lr) * 208 + s * 64 + qoff);
    acc[0] = __builtin_amdgcn_mfma_f32_16x16x32_bf16(a0, be0, acc[0], 0, 0, 0);
    acc[1] = __builtin_amdgcn_mfma_f32_16x16x32_bf16(a0, be1, acc[1], 0, 0, 0);
    acc[2] = __builtin_amdgcn_mfma_f32_16x16x32_bf16(a0, be2, acc[2], 0, 0, 0);
    acc[3] = __builtin_amdgcn_mfma_f32_16x16x32_bf16(a0, be3, acc[3], 0, 0, 0);
    acc[4] = __builtin_amdgcn_mfma_f32_16x16x32_bf16(a1, be0, acc[4], 0, 0, 0);
    acc[5] = __builtin_amdgcn_mfma_f32_16x16x32_bf16(a1, be1, acc[5], 0, 0, 0);
    acc[6] = __builtin_amdgcn_mfma_f32_16x16x32_bf16(a1, be2, acc[6], 0, 0, 0);
    acc[7] = __builtin_amdgcn_mfma_f32_16x16x32_bf16(a1, be3, acc[7], 0, 0, 0);
  }
  __syncthreads();   // edge_in reads done; alias LDS as H (64 x 280 bf16)

  // H[e][n] = gelu(D + PROJ_S[src][n] + PROJ_D[dst][n])   (b1 inside PROJ_S)
  {
    char* Hb = smem;
    #pragma unroll
    for (int c = 0; c < 2; ++c){
      int n = (c0 + c) * 16 + quad * 4;
      f32x4 pv[4], qv[4];
      #pragma unroll
      for (int t = 0; t < 4; ++t){
        pv[t] = *(const f32x4*)(ps + (size_t)lsrc[t * 16 + lr] * 256 + n);
        qv[t] = *(const f32x4*)(pd + (size_t)ldst[t * 16 + lr] * 256 + n);
      }
      #pragma unroll
      for (int t = 0; t < 4; ++t){
        int e = t * 16 + lr;
        f32x4 s4 = acc[c * 4 + t];
        float v0 = gelu_s(s4[0] + pv[t][0] + qv[t][0]);
        float v1 = gelu_s(s4[1] + pv[t][1] + qv[t][1]);
        float v2 = gelu_s(s4[2] + pv[t][2] + qv[t][2]);
        float v3 = gelu_s(s4[3] + pv[t][3] + qv[t][3]);
        uint2 p; p.x = pack_bf16(v0, v1); p.y = pack_bf16(v2, v3);
        *(uint2*)(Hb + e * 560 + n * 2) = p;
      }
    }
  }
  __syncthreads();

  // ---- GEMM2 (transposed): wave owns n-tiles {c2,c2+1} x e-tiles {eb,eb+16}
  int c2 = (w & 3) * 2;
  int eb = (w >> 2) * 32;
  f32x4 acc2[4];                    // [c*2 + t]
  #pragma unroll
  for (int i = 0; i < 4; ++i) acc2[i] = (f32x4){0.f, 0.f, 0.f, 0.f};
  const short8* w2f8 = (const short8*)w2f;
  #pragma unroll
  for (int s = 0; s < 8; ++s){
    short8 aa0 = w2f8[(s * 8 + c2 + 0) * 64 + lane];
    short8 aa1 = w2f8[(s * 8 + c2 + 1) * 64 + lane];
    short8 h0 = *(const short8*)(smem + (eb +  0 + lr) * 560 + s * 64 + qoff);
    short8 h1 = *(const short8*)(smem + (eb + 16 + lr) * 560 + s * 64 + qoff);
    acc2[0] = __builtin_amdgcn_mfma_f32_16x16x32_bf16(aa0, h0, acc2[0], 0, 0, 0);
    acc2[1] = __builtin_amdgcn_mfma_f32_16x16x32_bf16(aa0, h1, acc2[1], 0, 0, 0);
    acc2[2] = __builtin_amdgcn_mfma_f32_16x16x32_bf16(aa1, h0, acc2[2], 0, 0, 0);
    acc2[3] = __builtin_amdgcn_mfma_f32_16x16x32_bf16(aa1, h1, acc2[3], 0, 0, 0);
  }

  // output: lane writes 2 x f32x4 per edge (n0, n0+16) -> wave covers full
  // 128-B line of each of its 32 edge rows
  {
    int n0 = c2 * 16 + quad * 4;
    f32x4 bz0 = *(const f32x4*)(bias2 + n0);
    f32x4 bz1 = *(const f32x4*)(bias2 + n0 + 16);
    float* og = outp + (size_t)e0 * 128;
    #pragma unroll
    for (int t = 0; t < 2; ++t){
      int e = eb + t * 16 + lr;
      f32x4 v0, v1;
      v0[0] = acc2[t][0] + bz0[0]; v0[1] = acc2[t][1] + bz0[1];
      v0[2] = acc2[t][2] + bz0[2]; v0[3] = acc2[t][3] + bz0[3];
      v1[0] = acc2[2 + t][0] + bz1[0]; v1[1] = acc2[2 + t][1] + bz1[1];
      v1[2] = acc2[2 + t][2] + bz1[2]; v1[3] = acc2[2 + t][3] + bz1[3];
      *(f32x4*)(og + (size_t)e * 128 + n0)      = v0;
      *(f32x4*)(og + (size_t)e * 128 + n0 + 16) = v1;
    }
  }
}

extern "C" void kernel_launch(void* const* d_in, const int* in_sizes, int n_in,
                              void* d_out, int out_size, void* d_ws, size_t ws_size,
                              hipStream_t stream) {
  const float* emb    = (const float*)d_in[0];
  const float* ts     = (const float*)d_in[1];
  const float* coords = (const float*)d_in[2];
  const float* tf     = (const float*)d_in[3];
  const float* cf     = (const float*)d_in[4];
  const float* w1r    = (const float*)d_in[5];
  const float* b1r    = (const float*)d_in[6];
  const float* w2r    = (const float*)d_in[7];
  const float* b2r    = (const float*)d_in[8];
  const float* wg     = (const float*)d_in[9];
  const float* w1e    = (const float*)d_in[10];
  const float* b1e    = (const float*)d_in[11];
  const float* w2e    = (const float*)d_in[12];
  const float* b2e    = (const float*)d_in[13];
  const int* resi     = (const int*)d_in[14];
  const int* chain    = (const int*)d_in[15];
  const int* gia      = (const int*)d_in[16];
  const int* gib      = (const int*)d_in[17];
  const int* pid      = (const int*)d_in[18];

  char* ws = (char*)d_ws;
  float* RT            = (float*)(ws + WS_RT);
  unsigned short* W1F  = (unsigned short*)(ws + WS_W1F);
  unsigned short* W2F  = (unsigned short*)(ws + WS_W2F);
  float* PS            = (float*)(ws + WS_PS);
  float* PD            = (float*)(ws + WS_PD);
  unsigned short* W1RF = (unsigned short*)(ws + WS_W1RF);
  unsigned short* W2RF = (unsigned short*)(ws + WS_W2RF);
  float* outp          = (float*)d_out;

  hipLaunchKernelGGL(prep_k, dim3(176), dim3(256), 0, stream,
                     coords, RT, wg, w1e, W1F, w2e, W2F, w1r, W1RF, w2r, W2RF);
  hipLaunchKernelGGL(node_k, dim3(64), dim3(512), 0, stream,
                     emb, ts, tf, W1RF, b1r, W2RF, b2r, W1F, b1e, PS, PD);
  hipLaunchKernelGGL(edge_k, dim3(2080), dim3(512), 0, stream,
                     RT, cf, resi, chain, gia, gib, pid, W1F, W2F, PS, PD,
                     b2e, outp);
}